// Round 10
// baseline (247.984 us; speedup 1.0000x reference)
//
#include <hip/hip_runtime.h>
#include <hip/hip_fp16.h>

// GCN encoder: 3x GCNConv (+self-loops, sym deg^-1/2 norm) + ELU + mean-pool.
// N=50000, E=800000, IN=128, HID=64, ZDIM=64, G=64. f32 in/out.
// R16: S(hW)=(Sh)W -> one shared 64-dim gather. R17: 32-rows-in-flight
//     gather shape -> 238. R20: MFMA GEMMs -> 220. R21: launch fusion +
//     f16 g-buffer -> 217.1. R23: int2 edge path -> 216.0. R24: XCD-affine
//     split gather (no wave doubling) -> 214.4.
// Gather forensics (R16-R24): byte-halving, MLP x4, issue-diet, XCD
//     affinity each move gathers <=2% -> they sit at a random-transaction
//     service floor (~1.6M scattered 64-128B row reads each). Frozen.
// R25: FUSE gather_g INTO mm_pool. mm_pool's block consumes only its own
//     64 gh2 rows -> block-local dependency. Phase 1: 4 waves x 16 nodes,
//     R17 gather shape per node, g rows staged in LDS (gs[64][72] f16,
//     stride 144B for 16B-aligned half8). Phase 2: MFMA A-frags from LDS.
//     Removes the 12.8MB gh2 round-trip + one dependent launch.
//     hh unified (128B rows) for the fused consumer; gather_hh keeps
//     R24 split READS (tsA/tsB affinity) but writes unified hh.
//     Pre-commit: neutral/regression => pipeline at latency floor; final.

#define IN_DIM 128
#define HID 64
#define ZDIM 64
#define N_GRAPHS 64
#define SCAN_B 1024

typedef _Float16 half8 __attribute__((ext_vector_type(8)));
typedef float f32x4 __attribute__((ext_vector_type(4)));

__device__ __forceinline__ float elu1(float x) {
    return x > 0.f ? x : expm1f(x);
}

// Accumulate 8 fp16 (held in a float4 raw register) with mask MV into acc[8].
#define ACC8(RV, MV) do { \
    const __half2* _hp = (const __half2*)&(RV); \
    float2 _f0 = __half22float2(_hp[0]); \
    float2 _f1 = __half22float2(_hp[1]); \
    float2 _f2 = __half22float2(_hp[2]); \
    float2 _f3 = __half22float2(_hp[3]); \
    acc[0] = fmaf((MV), _f0.x, acc[0]); \
    acc[1] = fmaf((MV), _f0.y, acc[1]); \
    acc[2] = fmaf((MV), _f1.x, acc[2]); \
    acc[3] = fmaf((MV), _f1.y, acc[3]); \
    acc[4] = fmaf((MV), _f2.x, acc[4]); \
    acc[5] = fmaf((MV), _f2.y, acc[5]); \
    acc[6] = fmaf((MV), _f3.x, acc[6]); \
    acc[7] = fmaf((MV), _f3.y, acc[7]); \
  } while (0)

// Fused: edge counting (rank/deg, 2 edges/thread) + weight frag swizzle.
__global__ __launch_bounds__(256) void k_count_wfrag(const int* __restrict__ dst,
                                                     int* __restrict__ kc,
                                                     int* __restrict__ rank, int E,
                                                     const float* __restrict__ W1,
                                                     const float* __restrict__ Wmu,
                                                     const float* __restrict__ Wsig,
                                                     __half* __restrict__ F1,
                                                     __half* __restrict__ Fmu,
                                                     __half* __restrict__ Fsig,
                                                     int cntBlocks) {
    if ((int)blockIdx.x < cntBlocks) {
        int e = (blockIdx.x * 256 + threadIdx.x) * 2;
        if (e + 1 < E) {
            int2 d2 = *(const int2*)&dst[e];
            int r0 = atomicAdd(&kc[d2.x], 1);
            int r1 = atomicAdd(&kc[d2.y], 1);
            *(int2*)&rank[e] = make_int2(r0, r1);
        } else if (e < E) {
            rank[e] = atomicAdd(&kc[dst[e]], 1);
        }
        return;
    }
    int e = (blockIdx.x - cntBlocks) * 256 + threadIdx.x;
    if (e < 8192) {
        int j = e & 7, l = (e >> 3) & 63, ct = (e >> 9) & 3, ks = e >> 11;
        F1[e] = __float2half(W1[(ks * 32 + ((l >> 4) & 3) * 8 + j) * 64 + ct * 16 + (l & 15)]);
    }
    if (e < 4096) {
        int j = e & 7, l = (e >> 3) & 63, ct = (e >> 9) & 3, ks = e >> 11;
        int widx = (ks * 32 + ((l >> 4) & 3) * 8 + j) * 64 + ct * 16 + (l & 15);
        Fmu[e] = __float2half(Wmu[widx]);
        Fsig[e] = __float2half(Wsig[widx]);
    }
}

// S1: per-block sum of kc -> bsum[blk]
__global__ __launch_bounds__(SCAN_B) void k_scan1(const int* __restrict__ kc,
                                                  int* __restrict__ bsum, int n) {
    __shared__ int wpart[16];
    int tid = threadIdx.x, lane = tid & 63, w = tid >> 6;
    int i = blockIdx.x * SCAN_B + tid;
    int v = (i < n) ? kc[i] : 0;
#pragma unroll
    for (int d = 1; d < 64; d <<= 1) v += __shfl_xor(v, d, 64);
    if (lane == 0) wpart[w] = v;
    __syncthreads();
    if (tid < 16) {
        int t = wpart[tid];
#pragma unroll
        for (int d = 1; d < 16; d <<= 1) t += __shfl_xor(t, d, 64);
        if (tid == 0) bsum[blockIdx.x] = t;
    }
}

// S3: each block re-scans bsum in-register (nb<=64) for its base, then
// offs[i+1] = inclusive prefix, dinv[i] = 1/sqrt(1+kc[i]).
__global__ __launch_bounds__(SCAN_B) void k_scan3(const int* __restrict__ kc,
                                                  const int* __restrict__ bsum,
                                                  int* __restrict__ offs,
                                                  float* __restrict__ dinv,
                                                  int n, int nb) {
    __shared__ int wsum[16];
    __shared__ int sbase;
    int tid = threadIdx.x, lane = tid & 63, w = tid >> 6;
    if (tid < 64) {  // wave 0: exclusive prefix of bsum at blockIdx.x
        int v = (tid < nb) ? bsum[tid] : 0;
        int s = v;
#pragma unroll
        for (int d = 1; d < 64; d <<= 1) {
            int u = __shfl_up(s, d, 64);
            if (tid >= d) s += u;
        }
        if (tid == blockIdx.x) sbase = s - v;
    }
    int i = blockIdx.x * SCAN_B + tid;
    int v = (i < n) ? kc[i] : 0;
    int s = v;
#pragma unroll
    for (int d = 1; d < 64; d <<= 1) {
        int u = __shfl_up(s, d, 64);
        if (lane >= d) s += u;
    }
    if (lane == 63) wsum[w] = s;
    __syncthreads();
    if (tid < 16) {
        int t = wsum[tid];
#pragma unroll
        for (int d = 1; d < 16; d <<= 1) {
            int u = __shfl_up(t, d, 64);
            if (tid >= d) t += u;
        }
        wsum[tid] = t;
    }
    __syncthreads();
    int base = sbase + ((w == 0) ? 0 : wsum[w - 1]);
    if (i < n) {
        offs[i + 1] = base + s;
        dinv[i] = 1.0f / sqrtf(1.0f + (float)v);
        if (i == 0) offs[0] = 0;
    }
}

// Fused: atomic-free CSR fill (2 edges/thread) + MFMA mm1 with SPLIT
// epilogue: dims 0..31 -> tsA, 32..63 -> tsB (64B half-rows).
__global__ __launch_bounds__(256) void k_fill_mm1(const int* __restrict__ src,
                                                  const int* __restrict__ dst,
                                                  const int* __restrict__ rank,
                                                  const int* __restrict__ offs,
                                                  int* __restrict__ csr, int E,
                                                  const float* __restrict__ x,
                                                  const __half* __restrict__ F1,
                                                  const float* __restrict__ dinv,
                                                  __half* __restrict__ tsA,
                                                  __half* __restrict__ tsB, int n,
                                                  int fillBlocks) {
    if ((int)blockIdx.x < fillBlocks) {
        int e = (blockIdx.x * 256 + threadIdx.x) * 2;
        if (e + 1 < E) {
            int2 s2 = *(const int2*)&src[e];
            int2 d2 = *(const int2*)&dst[e];
            int2 r2 = *(const int2*)&rank[e];
            csr[offs[d2.x] + r2.x] = s2.x;
            csr[offs[d2.y] + r2.y] = s2.y;
        } else if (e < E) {
            csr[offs[dst[e]] + rank[e]] = src[e];
        }
        return;
    }
    int bid = blockIdx.x - fillBlocks;
    int l = threadIdx.x & 63;
    int wave = threadIdx.x >> 6;
    int m0 = bid * 64 + wave * 16;
    int row_a = m0 + (l & 15);
    if (row_a >= n) row_a = n - 1;  // clamp loads; stores guarded
    int kg = l >> 4;

    f32x4 acc0 = {0.f, 0.f, 0.f, 0.f};
    f32x4 acc1 = acc0, acc2 = acc0, acc3 = acc0;

    const float* xr = x + (size_t)row_a * IN_DIM + kg * 8;
#pragma unroll
    for (int ks = 0; ks < 4; ++ks) {
        float4 xa = *(const float4*)(xr + ks * 32);
        float4 xb = *(const float4*)(xr + ks * 32 + 4);
        half8 a;
        a[0] = (_Float16)xa.x; a[1] = (_Float16)xa.y;
        a[2] = (_Float16)xa.z; a[3] = (_Float16)xa.w;
        a[4] = (_Float16)xb.x; a[5] = (_Float16)xb.y;
        a[6] = (_Float16)xb.z; a[7] = (_Float16)xb.w;
        const __half* fb = F1 + ((size_t)(ks * 4) * 64 + l) * 8;
        half8 b0 = *(const half8*)(fb);
        half8 b1 = *(const half8*)(fb + 512);
        half8 b2 = *(const half8*)(fb + 1024);
        half8 b3 = *(const half8*)(fb + 1536);
        acc0 = __builtin_amdgcn_mfma_f32_16x16x32_f16(a, b0, acc0, 0, 0, 0);
        acc1 = __builtin_amdgcn_mfma_f32_16x16x32_f16(a, b1, acc1, 0, 0, 0);
        acc2 = __builtin_amdgcn_mfma_f32_16x16x32_f16(a, b2, acc2, 0, 0, 0);
        acc3 = __builtin_amdgcn_mfma_f32_16x16x32_f16(a, b3, acc3, 0, 0, 0);
    }
    int col = l & 15;
#pragma unroll
    for (int r = 0; r < 4; ++r) {
        int row = m0 + kg * 4 + r;  // C/D: row=(lane>>4)*4+reg, col=lane&15
        if (row < n) {
            float di = dinv[row];
            __half* pA = &tsA[(size_t)row * 32 + col];   // ct0 -> dim col
            pA[0]  = __float2half(acc0[r] * di);
            pA[16] = __float2half(acc1[r] * di);         // ct1 -> dim col+16
            __half* pB = &tsB[(size_t)row * 32 + col];   // ct2 -> dim 32+col
            pB[0]  = __float2half(acc2[r] * di);
            pB[16] = __float2half(acc3[r] * di);         // ct3 -> dim 48+col
        }
    }
}

// R24 gather (split READS, unified WRITE): wave = (node-pair, half).
// Lanes: nsel=lane>>5 picks node, l32=lane&31 -> g=l32>>2 row-group,
// sub=l32&3 16B chunk of the 64B half-row. Per node: 4 preloaded clamped
// batches = 32 rows in flight. Reduction: xor 4,8,16.
// hh[node][half*32 + e0..] = fp16(dinv * elu(dinv*(sum+self) + b1_half)).
__global__ __launch_bounds__(256) void k_gather_hh(const int* __restrict__ off,
                                                   const int* __restrict__ csr,
                                                   const float* __restrict__ dinv,
                                                   const __half* __restrict__ tsA,
                                                   const __half* __restrict__ tsB,
                                                   const float* __restrict__ b1,
                                                   __half* __restrict__ hh, int n) {
    int bid = blockIdx.x;
    int half = (bid >> 2) & 1;
    int jb = (bid >> 3) * 4 + (bid & 3);
    int wv = threadIdx.x >> 6;
    int node0 = jb * 8 + wv * 2;
    if (node0 >= n) return;
    const __half* T = half ? tsB : tsA;
    int lane = threadIdx.x & 63;
    int nsel = lane >> 5;
    int node = node0 + nsel;
    bool valid = node < n;
    int nodec = valid ? node : n - 1;
    int l32 = lane & 31, g = l32 >> 2, sub = l32 & 3;
    int s0 = off[nodec], s1 = off[nodec + 1];
    float acc[8];
#pragma unroll
    for (int j = 0; j < 8; ++j) acc[j] = 0.f;

    if (s1 > s0) {
        int last = s1 - 1;
        int p0 = s0 + g, p1 = p0 + 8, p2 = p0 + 16, p3 = p0 + 24;
        int i0 = csr[p0 < s1 ? p0 : last];
        int i1 = csr[p1 < s1 ? p1 : last];
        int i2 = csr[p2 < s1 ? p2 : last];
        int i3 = csr[p3 < s1 ? p3 : last];
        float4 r0 = *(const float4*)&T[(size_t)i0 * 32 + sub * 8];
        float4 r1 = *(const float4*)&T[(size_t)i1 * 32 + sub * 8];
        float4 r2 = *(const float4*)&T[(size_t)i2 * 32 + sub * 8];
        float4 r3 = *(const float4*)&T[(size_t)i3 * 32 + sub * 8];
        float m0 = (p0 < s1) ? 1.f : 0.f;
        float m1 = (p1 < s1) ? 1.f : 0.f;
        float m2 = (p2 < s1) ? 1.f : 0.f;
        float m3 = (p3 < s1) ? 1.f : 0.f;
        ACC8(r0, m0);
        ACC8(r1, m1);
        ACC8(r2, m2);
        ACC8(r3, m3);
        for (int k = s0 + 32 + g; k < s1; k += 8) {  // rare (deg>32)
            int iv = csr[k];
            float4 rv = *(const float4*)&T[(size_t)iv * 32 + sub * 8];
            ACC8(rv, 1.f);
        }
    }

#pragma unroll
    for (int j = 0; j < 8; ++j) {
        acc[j] += __shfl_xor(acc[j], 4, 64);
        acc[j] += __shfl_xor(acc[j], 8, 64);
        acc[j] += __shfl_xor(acc[j], 16, 64);
    }

    if (g == 0 && valid) {  // per node: 4 lanes (sub), 8 dims each
        int e0 = sub * 8;   // dim within the half
        float4 sr = *(const float4*)&T[(size_t)nodec * 32 + e0];
        const __half2* sh = (const __half2*)&sr;
        float di = dinv[nodec];
        const float* bh = b1 + half * 32 + e0;
        float4 ba = *(const float4*)bh;
        float4 bb = *(const float4*)(bh + 4);
        float2 f0 = __half22float2(sh[0]);
        float2 f1 = __half22float2(sh[1]);
        float2 f2 = __half22float2(sh[2]);
        float2 f3 = __half22float2(sh[3]);
        float e0v = elu1((acc[0] + f0.x) * di + ba.x) * di;
        float e1v = elu1((acc[1] + f0.y) * di + ba.y) * di;
        float e2v = elu1((acc[2] + f1.x) * di + ba.z) * di;
        float e3v = elu1((acc[3] + f1.y) * di + ba.w) * di;
        float e4v = elu1((acc[4] + f2.x) * di + bb.x) * di;
        float e5v = elu1((acc[5] + f2.y) * di + bb.y) * di;
        float e6v = elu1((acc[6] + f3.x) * di + bb.z) * di;
        float e7v = elu1((acc[7] + f3.y) * di + bb.w) * di;
        float4 outv;
        __half2* op = (__half2*)&outv;
        op[0] = __floats2half2_rn(e0v, e1v);
        op[1] = __floats2half2_rn(e2v, e3v);
        op[2] = __floats2half2_rn(e4v, e5v);
        op[3] = __floats2half2_rn(e6v, e7v);
        *(float4*)&hh[(size_t)node * 64 + half * 32 + e0] = outv;
    }
}

// FUSED layers-2/3 gather + mu|sig MFMA GEMM + bias + elu + pool stage-1.
// Phase 1: 4 waves x 16 nodes (R17 gather shape per node, hh 128B rows),
//   g rows -> LDS gs[64][72] f16 (144B stride: 16B-aligned half8 rows).
// Phase 2: MFMA A-frags from LDS, B-frags from Fmu/Fsig; P -> wc; LDS
//   column-reduce pool with boundary-flush atomics into sums.
__global__ __launch_bounds__(256) void k_mmg_pool(const int* __restrict__ off,
                                                  const int* __restrict__ csr,
                                                  const float* __restrict__ dinv,
                                                  const __half* __restrict__ hh,
                                                  const __half* __restrict__ Fmu,
                                                  const __half* __restrict__ Fsig,
                                                  const float* __restrict__ bmu,
                                                  const float* __restrict__ bsig,
                                                  const int* __restrict__ batch,
                                                  float* __restrict__ sums, int n) {
    __shared__ float wc[64 * 132];
    __shared__ __half gs[64 * 72];
    __shared__ int bs[64];
    const int tid = threadIdx.x;
    int lane = tid & 63, wave = tid >> 6;
    int m0 = blockIdx.x * 64;
    int g = lane >> 3, sub = lane & 7;

    // Phase 1: gather g = S*h for this block's 64 nodes (16 per wave).
    for (int t = 0; t < 16; ++t) {
        int node = m0 + wave * 16 + t;       // wave-uniform
        bool valid = node < n;
        int nodec = valid ? node : n - 1;
        int s0 = off[nodec], s1 = off[nodec + 1];
        float acc[8];
#pragma unroll
        for (int j = 0; j < 8; ++j) acc[j] = 0.f;

        if (s1 > s0) {
            int last = s1 - 1;
            int p0 = s0 + g, p1 = p0 + 8, p2 = p0 + 16, p3 = p0 + 24;
            int i0 = csr[p0 < s1 ? p0 : last];
            int i1 = csr[p1 < s1 ? p1 : last];
            int i2 = csr[p2 < s1 ? p2 : last];
            int i3 = csr[p3 < s1 ? p3 : last];
            float4 r0 = *(const float4*)&hh[(size_t)i0 * 64 + sub * 8];
            float4 r1 = *(const float4*)&hh[(size_t)i1 * 64 + sub * 8];
            float4 r2 = *(const float4*)&hh[(size_t)i2 * 64 + sub * 8];
            float4 r3 = *(const float4*)&hh[(size_t)i3 * 64 + sub * 8];
            float m0v = (p0 < s1) ? 1.f : 0.f;
            float m1v = (p1 < s1) ? 1.f : 0.f;
            float m2v = (p2 < s1) ? 1.f : 0.f;
            float m3v = (p3 < s1) ? 1.f : 0.f;
            ACC8(r0, m0v);
            ACC8(r1, m1v);
            ACC8(r2, m2v);
            ACC8(r3, m3v);
            for (int k = s0 + 32 + g; k < s1; k += 8) {  // rare (deg>32)
                int iv = csr[k];
                float4 rv = *(const float4*)&hh[(size_t)iv * 64 + sub * 8];
                ACC8(rv, 1.f);
            }
        }

#pragma unroll
        for (int j = 0; j < 8; ++j) {
            acc[j] += __shfl_xor(acc[j], 8, 64);
            acc[j] += __shfl_xor(acc[j], 16, 64);
            acc[j] += __shfl_xor(acc[j], 32, 64);
        }

        if (g == 0) {
            int row = wave * 16 + t;
            float4 outv = make_float4(0.f, 0.f, 0.f, 0.f);
            if (valid) {
                float4 sr = *(const float4*)&hh[(size_t)nodec * 64 + sub * 8];
                const __half2* sh = (const __half2*)&sr;
                float di = dinv[nodec];
                float2 f0 = __half22float2(sh[0]);
                float2 f1 = __half22float2(sh[1]);
                float2 f2 = __half22float2(sh[2]);
                float2 f3 = __half22float2(sh[3]);
                __half2* op = (__half2*)&outv;
                op[0] = __floats2half2_rn((acc[0] + f0.x) * di, (acc[1] + f0.y) * di);
                op[1] = __floats2half2_rn((acc[2] + f1.x) * di, (acc[3] + f1.y) * di);
                op[2] = __floats2half2_rn((acc[4] + f2.x) * di, (acc[5] + f2.y) * di);
                op[3] = __floats2half2_rn((acc[6] + f3.x) * di, (acc[7] + f3.y) * di);
            }
            *(float4*)&gs[row * 72 + sub * 8] = outv;
        }
    }
    if (tid < 64) bs[tid] = (m0 + tid < n) ? batch[m0 + tid] : -1;
    __syncthreads();

    // Phase 2: MFMA from LDS.
    int row_l = wave * 16 + (lane & 15);
    int kg = lane >> 4;

    f32x4 am[4], as[4];
#pragma unroll
    for (int ct = 0; ct < 4; ++ct) {
        am[ct] = (f32x4){0.f, 0.f, 0.f, 0.f};
        as[ct] = (f32x4){0.f, 0.f, 0.f, 0.f};
    }

#pragma unroll
    for (int ks = 0; ks < 2; ++ks) {
        half8 a = *(const half8*)&gs[row_l * 72 + kg * 8 + ks * 32];
        const __half* fm = Fmu + ((size_t)(ks * 4) * 64 + lane) * 8;
        const __half* fs = Fsig + ((size_t)(ks * 4) * 64 + lane) * 8;
#pragma unroll
        for (int ct = 0; ct < 4; ++ct) {
            half8 bm = *(const half8*)(fm + ct * 512);
            half8 bv = *(const half8*)(fs + ct * 512);
            am[ct] = __builtin_amdgcn_mfma_f32_16x16x32_f16(a, bm, am[ct], 0, 0, 0);
            as[ct] = __builtin_amdgcn_mfma_f32_16x16x32_f16(a, bv, as[ct], 0, 0, 0);
        }
    }

    int col = lane & 15;
#pragma unroll
    for (int ct = 0; ct < 4; ++ct) {
        float bM = bmu[ct * 16 + col];
        float bS = bsig[ct * 16 + col];
#pragma unroll
        for (int r = 0; r < 4; ++r) {
            int rr = wave * 16 + kg * 4 + r;  // C/D row mapping
            wc[rr * 132 + ct * 16 + col] = elu1(am[ct][r] + bM);
            wc[rr * 132 + 64 + ct * 16 + col] = elu1(as[ct][r] + bS);
        }
    }
    __syncthreads();

    // Pool: thread (d, seg) reduces column d over rows [seg*32, seg*32+32),
    // flushing at graph boundaries (batch sorted).
    int d = tid & 127, seg = tid >> 7;
    int base = (d < 64) ? d : (64 * 64 - 64 + d);  // mu: g*64+d, sig: 4096+g*64+(d-64)
    float acc = 0.f;
    int gcur = -1;
    int r0 = seg * 32;
    for (int r = r0; r < r0 + 32; ++r) {
        int gb = bs[r];
        if (gb < 0) break;
        float v = wc[r * 132 + d];
        if (gb != gcur) {
            if (gcur >= 0) atomicAdd(&sums[base + gcur * 64], acc);
            acc = 0.f;
            gcur = gb;
        }
        acc += v;
    }
    if (gcur >= 0) atomicAdd(&sums[base + gcur * 64], acc);
}

// Pool stage 2: one thread per output element; cnt via binary search.
__global__ void k_pool_final(const float* __restrict__ sums,
                             const int* __restrict__ batch,
                             float* __restrict__ out, int n) {
    int i = blockIdx.x * blockDim.x + threadIdx.x;
    if (i >= 2 * N_GRAPHS * ZDIM) return;
    int g = (i >> 6) & 63;
    int lo = 0, hi = n;
    while (lo < hi) { int m = (lo + hi) >> 1; if (batch[m] < g) lo = m + 1; else hi = m; }
    int s = lo;
    lo = s; hi = n;
    while (lo < hi) { int m = (lo + hi) >> 1; if (batch[m] < g + 1) lo = m + 1; else hi = m; }
    float c = fmaxf((float)(lo - s), 1.0f);
    out[i] = sums[i] / c;
}

extern "C" void kernel_launch(void* const* d_in, const int* in_sizes, int n_in,
                              void* d_out, int out_size, void* d_ws, size_t ws_size,
                              hipStream_t stream) {
    const float* x    = (const float*)d_in[0];
    const int*   ei   = (const int*)d_in[1];
    const int*   batch= (const int*)d_in[2];
    // d_in[3] = num_graphs (scalar, known 64)
    const float* W1   = (const float*)d_in[4];
    const float* b1   = (const float*)d_in[5];
    const float* Wmu  = (const float*)d_in[6];
    const float* bmu  = (const float*)d_in[7];
    const float* Wsig = (const float*)d_in[8];
    const float* bsig = (const float*)d_in[9];
    float* out = (float*)d_out;

    const int n = in_sizes[0] / IN_DIM;   // 50000
    const int E = in_sizes[1] / 2;        // 800000
    const int* src = ei;
    const int* dst = ei + E;
    const int NSB = (n + SCAN_B - 1) / SCAN_B;  // scan blocks (49)

    float* ws = (float*)d_ws;
    size_t off_w = 0;
    int*   kc   = (int*)(ws + off_w); off_w += 50048;
    float* sums = ws + off_w; off_w += 8192;   // contiguous with kc: one memset
    float* dinv = ws + off_w; off_w += 50048;
    int*   offs = (int*)(ws + off_w); off_w += 50056;
    int*   bsum = (int*)(ws + off_w); off_w += 64;
    int*   rank = (int*)(ws + off_w); off_w += 800000;
    int*   csr  = (int*)(ws + off_w); off_w += 800000;
    off_w = (off_w + 15) & ~(size_t)15;
    __half* F1   = (__half*)(ws + off_w); off_w += 4096;  // 8192 halfs
    __half* Fmu  = (__half*)(ws + off_w); off_w += 2048;  // 4096 halfs
    __half* Fsig = (__half*)(ws + off_w); off_w += 2048;  // 4096 halfs
    const size_t HALFF = (size_t)50048 * 16;  // n*32 halfs, in float units
    __half* tsA = (__half*)(ws + off_w); off_w += HALFF;  // dims 0..31
    __half* tsB = (__half*)(ws + off_w); off_w += HALFF;  // dims 32..63
    __half* hh  = (__half*)(ws + off_w); off_w += (size_t)50048 * 32;  // unified n*64

    const int gE2 = (E + 511) / 512;  // 2-edges-per-thread blocks (1563)
    const int NB  = (n + 63) / 64;    // 64-node GEMM tiles
    const int bph = (n + 7) / 8;      // gather blocks per half (8 nodes/blk)
    const int bph4 = (bph + 3) & ~3;  // multiple of 4 -> grid multiple of 8
    const int gG = 2 * bph4;          // split-half gather grid

    // CSR build + normalization (kc+sums zeroed in ONE contiguous memset)
    hipMemsetAsync(kc, 0, (50048 + 8192) * sizeof(int), stream);
    k_count_wfrag<<<gE2 + 32, 256, 0, stream>>>(dst, kc, rank, E,
                                                W1, Wmu, Wsig, F1, Fmu, Fsig, gE2);
    k_scan1<<<NSB, SCAN_B, 0, stream>>>(kc, bsum, n);
    k_scan3<<<NSB, SCAN_B, 0, stream>>>(kc, bsum, offs, dinv, n, NSB);

    // CSR fill + layer-1 MFMA GEMM (split ts epilogue)
    k_fill_mm1<<<gE2 + NB, 256, 0, stream>>>(src, dst, rank, offs, csr, E,
                                             x, F1, dinv, tsA, tsB, n, gE2);

    // layer 1 gather: hh = fp16(dinv*elu(S(xW1)+b1)), split reads / unified write
    k_gather_hh<<<gG, 256, 0, stream>>>(offs, csr, dinv, tsA, tsB, b1, hh, n);

    // FUSED: layers-2/3 shared gather (LDS-staged) + mu|sig MFMA + pool
    k_mmg_pool<<<NB, 256, 0, stream>>>(offs, csr, dinv, hh, Fmu, Fsig,
                                       bmu, bsig, batch, sums, n);
    k_pool_final<<<(2 * N_GRAPHS * ZDIM + 255) / 256, 256, 0, stream>>>(sums, batch, out, n);
}

// Round 11
// 213.867 us; speedup vs baseline: 1.1595x; 1.1595x over previous
//
#include <hip/hip_runtime.h>
#include <hip/hip_fp16.h>

// GCN encoder: 3x GCNConv (+self-loops, sym deg^-1/2 norm) + ELU + mean-pool.
// N=50000, E=800000, IN=128, HID=64, ZDIM=64, G=64. f32 in/out.
// R16: S(hW)=(Sh)W -> one shared 64-dim gather. R17: 32-rows-in-flight
//     gather shape -> 238. R20: MFMA GEMMs -> 220. R21: launch fusion +
//     f16 g-buffer -> 217.1. R23: int2 edge path -> 216.0. R24: XCD-affine
//     split gather (no wave doubling) -> 214.4 BEST.
// R25: gather_g fused into mm_pool FAILED (248.0): 43.5KB LDS -> occupancy
//     17.9% (3 blk/CU); the latency-bound gather lives off TLP. Gathers
//     need a dedicated LDS-light high-occupancy kernel. REVERTED to R24.
// Gather forensics complete (R16-R25): byte-halving, MLP x4, issue-diet,
//     XCD affinity, fusion - all <=2% or regress. The two gathers (~45us
//     each) sit at a scattered-transaction service floor (~1.6M independent
//     64-128B row reads; 13% HBM, 22% VALU, FETCH at compulsory-broadcast
//     floor). Structure final.

#define IN_DIM 128
#define HID 64
#define ZDIM 64
#define N_GRAPHS 64
#define SCAN_B 1024

typedef _Float16 half8 __attribute__((ext_vector_type(8)));
typedef float f32x4 __attribute__((ext_vector_type(4)));

__device__ __forceinline__ float elu1(float x) {
    return x > 0.f ? x : expm1f(x);
}

// Accumulate 8 fp16 (held in a float4 raw register) with mask MV into acc[8].
#define ACC8(RV, MV) do { \
    const __half2* _hp = (const __half2*)&(RV); \
    float2 _f0 = __half22float2(_hp[0]); \
    float2 _f1 = __half22float2(_hp[1]); \
    float2 _f2 = __half22float2(_hp[2]); \
    float2 _f3 = __half22float2(_hp[3]); \
    acc[0] = fmaf((MV), _f0.x, acc[0]); \
    acc[1] = fmaf((MV), _f0.y, acc[1]); \
    acc[2] = fmaf((MV), _f1.x, acc[2]); \
    acc[3] = fmaf((MV), _f1.y, acc[3]); \
    acc[4] = fmaf((MV), _f2.x, acc[4]); \
    acc[5] = fmaf((MV), _f2.y, acc[5]); \
    acc[6] = fmaf((MV), _f3.x, acc[6]); \
    acc[7] = fmaf((MV), _f3.y, acc[7]); \
  } while (0)

// Fused: edge counting (rank/deg, 2 edges/thread) + weight frag swizzle.
__global__ __launch_bounds__(256) void k_count_wfrag(const int* __restrict__ dst,
                                                     int* __restrict__ kc,
                                                     int* __restrict__ rank, int E,
                                                     const float* __restrict__ W1,
                                                     const float* __restrict__ Wmu,
                                                     const float* __restrict__ Wsig,
                                                     __half* __restrict__ F1,
                                                     __half* __restrict__ Fmu,
                                                     __half* __restrict__ Fsig,
                                                     int cntBlocks) {
    if ((int)blockIdx.x < cntBlocks) {
        int e = (blockIdx.x * 256 + threadIdx.x) * 2;
        if (e + 1 < E) {
            int2 d2 = *(const int2*)&dst[e];
            int r0 = atomicAdd(&kc[d2.x], 1);
            int r1 = atomicAdd(&kc[d2.y], 1);
            *(int2*)&rank[e] = make_int2(r0, r1);
        } else if (e < E) {
            rank[e] = atomicAdd(&kc[dst[e]], 1);
        }
        return;
    }
    int e = (blockIdx.x - cntBlocks) * 256 + threadIdx.x;
    if (e < 8192) {
        int j = e & 7, l = (e >> 3) & 63, ct = (e >> 9) & 3, ks = e >> 11;
        F1[e] = __float2half(W1[(ks * 32 + ((l >> 4) & 3) * 8 + j) * 64 + ct * 16 + (l & 15)]);
    }
    if (e < 4096) {
        int j = e & 7, l = (e >> 3) & 63, ct = (e >> 9) & 3, ks = e >> 11;
        int widx = (ks * 32 + ((l >> 4) & 3) * 8 + j) * 64 + ct * 16 + (l & 15);
        Fmu[e] = __float2half(Wmu[widx]);
        Fsig[e] = __float2half(Wsig[widx]);
    }
}

// S1: per-block sum of kc -> bsum[blk]
__global__ __launch_bounds__(SCAN_B) void k_scan1(const int* __restrict__ kc,
                                                  int* __restrict__ bsum, int n) {
    __shared__ int wpart[16];
    int tid = threadIdx.x, lane = tid & 63, w = tid >> 6;
    int i = blockIdx.x * SCAN_B + tid;
    int v = (i < n) ? kc[i] : 0;
#pragma unroll
    for (int d = 1; d < 64; d <<= 1) v += __shfl_xor(v, d, 64);
    if (lane == 0) wpart[w] = v;
    __syncthreads();
    if (tid < 16) {
        int t = wpart[tid];
#pragma unroll
        for (int d = 1; d < 16; d <<= 1) t += __shfl_xor(t, d, 64);
        if (tid == 0) bsum[blockIdx.x] = t;
    }
}

// S3: each block re-scans bsum in-register (nb<=64) for its base, then
// offs[i+1] = inclusive prefix, dinv[i] = 1/sqrt(1+kc[i]).
__global__ __launch_bounds__(SCAN_B) void k_scan3(const int* __restrict__ kc,
                                                  const int* __restrict__ bsum,
                                                  int* __restrict__ offs,
                                                  float* __restrict__ dinv,
                                                  int n, int nb) {
    __shared__ int wsum[16];
    __shared__ int sbase;
    int tid = threadIdx.x, lane = tid & 63, w = tid >> 6;
    if (tid < 64) {  // wave 0: exclusive prefix of bsum at blockIdx.x
        int v = (tid < nb) ? bsum[tid] : 0;
        int s = v;
#pragma unroll
        for (int d = 1; d < 64; d <<= 1) {
            int u = __shfl_up(s, d, 64);
            if (tid >= d) s += u;
        }
        if (tid == blockIdx.x) sbase = s - v;
    }
    int i = blockIdx.x * SCAN_B + tid;
    int v = (i < n) ? kc[i] : 0;
    int s = v;
#pragma unroll
    for (int d = 1; d < 64; d <<= 1) {
        int u = __shfl_up(s, d, 64);
        if (lane >= d) s += u;
    }
    if (lane == 63) wsum[w] = s;
    __syncthreads();
    if (tid < 16) {
        int t = wsum[tid];
#pragma unroll
        for (int d = 1; d < 16; d <<= 1) {
            int u = __shfl_up(t, d, 64);
            if (tid >= d) t += u;
        }
        wsum[tid] = t;
    }
    __syncthreads();
    int base = sbase + ((w == 0) ? 0 : wsum[w - 1]);
    if (i < n) {
        offs[i + 1] = base + s;
        dinv[i] = 1.0f / sqrtf(1.0f + (float)v);
        if (i == 0) offs[0] = 0;
    }
}

// Fused: atomic-free CSR fill (2 edges/thread) + MFMA mm1 with SPLIT
// epilogue: dims 0..31 -> tsA, 32..63 -> tsB (64B half-rows).
__global__ __launch_bounds__(256) void k_fill_mm1(const int* __restrict__ src,
                                                  const int* __restrict__ dst,
                                                  const int* __restrict__ rank,
                                                  const int* __restrict__ offs,
                                                  int* __restrict__ csr, int E,
                                                  const float* __restrict__ x,
                                                  const __half* __restrict__ F1,
                                                  const float* __restrict__ dinv,
                                                  __half* __restrict__ tsA,
                                                  __half* __restrict__ tsB, int n,
                                                  int fillBlocks) {
    if ((int)blockIdx.x < fillBlocks) {
        int e = (blockIdx.x * 256 + threadIdx.x) * 2;
        if (e + 1 < E) {
            int2 s2 = *(const int2*)&src[e];
            int2 d2 = *(const int2*)&dst[e];
            int2 r2 = *(const int2*)&rank[e];
            csr[offs[d2.x] + r2.x] = s2.x;
            csr[offs[d2.y] + r2.y] = s2.y;
        } else if (e < E) {
            csr[offs[dst[e]] + rank[e]] = src[e];
        }
        return;
    }
    int bid = blockIdx.x - fillBlocks;
    int l = threadIdx.x & 63;
    int wave = threadIdx.x >> 6;
    int m0 = bid * 64 + wave * 16;
    int row_a = m0 + (l & 15);
    if (row_a >= n) row_a = n - 1;  // clamp loads; stores guarded
    int kg = l >> 4;

    f32x4 acc0 = {0.f, 0.f, 0.f, 0.f};
    f32x4 acc1 = acc0, acc2 = acc0, acc3 = acc0;

    const float* xr = x + (size_t)row_a * IN_DIM + kg * 8;
#pragma unroll
    for (int ks = 0; ks < 4; ++ks) {
        float4 xa = *(const float4*)(xr + ks * 32);
        float4 xb = *(const float4*)(xr + ks * 32 + 4);
        half8 a;
        a[0] = (_Float16)xa.x; a[1] = (_Float16)xa.y;
        a[2] = (_Float16)xa.z; a[3] = (_Float16)xa.w;
        a[4] = (_Float16)xb.x; a[5] = (_Float16)xb.y;
        a[6] = (_Float16)xb.z; a[7] = (_Float16)xb.w;
        const __half* fb = F1 + ((size_t)(ks * 4) * 64 + l) * 8;
        half8 b0 = *(const half8*)(fb);
        half8 b1 = *(const half8*)(fb + 512);
        half8 b2 = *(const half8*)(fb + 1024);
        half8 b3 = *(const half8*)(fb + 1536);
        acc0 = __builtin_amdgcn_mfma_f32_16x16x32_f16(a, b0, acc0, 0, 0, 0);
        acc1 = __builtin_amdgcn_mfma_f32_16x16x32_f16(a, b1, acc1, 0, 0, 0);
        acc2 = __builtin_amdgcn_mfma_f32_16x16x32_f16(a, b2, acc2, 0, 0, 0);
        acc3 = __builtin_amdgcn_mfma_f32_16x16x32_f16(a, b3, acc3, 0, 0, 0);
    }
    int col = l & 15;
#pragma unroll
    for (int r = 0; r < 4; ++r) {
        int row = m0 + kg * 4 + r;  // C/D: row=(lane>>4)*4+reg, col=lane&15
        if (row < n) {
            float di = dinv[row];
            __half* pA = &tsA[(size_t)row * 32 + col];   // ct0 -> dim col
            pA[0]  = __float2half(acc0[r] * di);
            pA[16] = __float2half(acc1[r] * di);         // ct1 -> dim col+16
            __half* pB = &tsB[(size_t)row * 32 + col];   // ct2 -> dim 32+col
            pB[0]  = __float2half(acc2[r] * di);
            pB[16] = __float2half(acc3[r] * di);         // ct3 -> dim 48+col
        }
    }
}

// R24 gather: wave = (node-pair, half). Lanes: nsel=lane>>5 picks node,
// l32=lane&31 -> g=l32>>2 row-group, sub=l32&3 16B chunk of the 64B
// half-row. Per node: 4 preloaded clamped batches = 32 rows in flight
// (R17-equal). Reduction: xor 4,8,16 within the node's 32 lanes.
// hhX[i] = fp16(dinv * elu(dinv*(sum+self) + b1_half)).
__global__ __launch_bounds__(256) void k_gather_hh(const int* __restrict__ off,
                                                   const int* __restrict__ csr,
                                                   const float* __restrict__ dinv,
                                                   const __half* __restrict__ tsA,
                                                   const __half* __restrict__ tsB,
                                                   const float* __restrict__ b1,
                                                   __half* __restrict__ hhA,
                                                   __half* __restrict__ hhB, int n) {
    int bid = blockIdx.x;
    int half = (bid >> 2) & 1;
    int jb = (bid >> 3) * 4 + (bid & 3);
    int wv = threadIdx.x >> 6;
    int node0 = jb * 8 + wv * 2;
    if (node0 >= n) return;
    const __half* T = half ? tsB : tsA;
    __half* H = half ? hhB : hhA;
    int lane = threadIdx.x & 63;
    int nsel = lane >> 5;
    int node = node0 + nsel;
    bool valid = node < n;
    int nodec = valid ? node : n - 1;
    int l32 = lane & 31, g = l32 >> 2, sub = l32 & 3;
    int s0 = off[nodec], s1 = off[nodec + 1];
    float acc[8];
#pragma unroll
    for (int j = 0; j < 8; ++j) acc[j] = 0.f;

    if (s1 > s0) {
        int last = s1 - 1;
        int p0 = s0 + g, p1 = p0 + 8, p2 = p0 + 16, p3 = p0 + 24;
        int i0 = csr[p0 < s1 ? p0 : last];
        int i1 = csr[p1 < s1 ? p1 : last];
        int i2 = csr[p2 < s1 ? p2 : last];
        int i3 = csr[p3 < s1 ? p3 : last];
        float4 r0 = *(const float4*)&T[(size_t)i0 * 32 + sub * 8];
        float4 r1 = *(const float4*)&T[(size_t)i1 * 32 + sub * 8];
        float4 r2 = *(const float4*)&T[(size_t)i2 * 32 + sub * 8];
        float4 r3 = *(const float4*)&T[(size_t)i3 * 32 + sub * 8];
        float m0 = (p0 < s1) ? 1.f : 0.f;
        float m1 = (p1 < s1) ? 1.f : 0.f;
        float m2 = (p2 < s1) ? 1.f : 0.f;
        float m3 = (p3 < s1) ? 1.f : 0.f;
        ACC8(r0, m0);
        ACC8(r1, m1);
        ACC8(r2, m2);
        ACC8(r3, m3);
        for (int k = s0 + 32 + g; k < s1; k += 8) {  // rare (deg>32)
            int iv = csr[k];
            float4 rv = *(const float4*)&T[(size_t)iv * 32 + sub * 8];
            ACC8(rv, 1.f);
        }
    }

#pragma unroll
    for (int j = 0; j < 8; ++j) {
        acc[j] += __shfl_xor(acc[j], 4, 64);
        acc[j] += __shfl_xor(acc[j], 8, 64);
        acc[j] += __shfl_xor(acc[j], 16, 64);
    }

    if (g == 0 && valid) {  // per node: 4 lanes (sub), 8 dims each
        int e0 = sub * 8;   // dim within the half
        float4 sr = *(const float4*)&T[(size_t)nodec * 32 + e0];
        const __half2* sh = (const __half2*)&sr;
        float di = dinv[nodec];
        const float* bh = b1 + half * 32 + e0;
        float4 ba = *(const float4*)bh;
        float4 bb = *(const float4*)(bh + 4);
        float2 f0 = __half22float2(sh[0]);
        float2 f1 = __half22float2(sh[1]);
        float2 f2 = __half22float2(sh[2]);
        float2 f3 = __half22float2(sh[3]);
        float e0v = elu1((acc[0] + f0.x) * di + ba.x) * di;
        float e1v = elu1((acc[1] + f0.y) * di + ba.y) * di;
        float e2v = elu1((acc[2] + f1.x) * di + ba.z) * di;
        float e3v = elu1((acc[3] + f1.y) * di + ba.w) * di;
        float e4v = elu1((acc[4] + f2.x) * di + bb.x) * di;
        float e5v = elu1((acc[5] + f2.y) * di + bb.y) * di;
        float e6v = elu1((acc[6] + f3.x) * di + bb.z) * di;
        float e7v = elu1((acc[7] + f3.y) * di + bb.w) * di;
        float4 outv;
        __half2* op = (__half2*)&outv;
        op[0] = __floats2half2_rn(e0v, e1v);
        op[1] = __floats2half2_rn(e2v, e3v);
        op[2] = __floats2half2_rn(e4v, e5v);
        op[3] = __floats2half2_rn(e6v, e7v);
        *(float4*)&H[(size_t)node * 32 + e0] = outv;
    }
}

// R24 layers-2/3 SHARED gather, same (node-pair, half) structure:
// gh2[node][half*32 + e0 ..] = f16(dinv*(sum + hh_half[node])).
__global__ __launch_bounds__(256) void k_gather_g(const int* __restrict__ off,
                                                  const int* __restrict__ csr,
                                                  const float* __restrict__ dinv,
                                                  const __half* __restrict__ hhA,
                                                  const __half* __restrict__ hhB,
                                                  __half* __restrict__ gh2, int n) {
    int bid = blockIdx.x;
    int half = (bid >> 2) & 1;
    int jb = (bid >> 3) * 4 + (bid & 3);
    int wv = threadIdx.x >> 6;
    int node0 = jb * 8 + wv * 2;
    if (node0 >= n) return;
    const __half* T = half ? hhB : hhA;
    int lane = threadIdx.x & 63;
    int nsel = lane >> 5;
    int node = node0 + nsel;
    bool valid = node < n;
    int nodec = valid ? node : n - 1;
    int l32 = lane & 31, g = l32 >> 2, sub = l32 & 3;
    int s0 = off[nodec], s1 = off[nodec + 1];
    float acc[8];
#pragma unroll
    for (int j = 0; j < 8; ++j) acc[j] = 0.f;

    if (s1 > s0) {
        int last = s1 - 1;
        int p0 = s0 + g, p1 = p0 + 8, p2 = p0 + 16, p3 = p0 + 24;
        int i0 = csr[p0 < s1 ? p0 : last];
        int i1 = csr[p1 < s1 ? p1 : last];
        int i2 = csr[p2 < s1 ? p2 : last];
        int i3 = csr[p3 < s1 ? p3 : last];
        float4 r0 = *(const float4*)&T[(size_t)i0 * 32 + sub * 8];
        float4 r1 = *(const float4*)&T[(size_t)i1 * 32 + sub * 8];
        float4 r2 = *(const float4*)&T[(size_t)i2 * 32 + sub * 8];
        float4 r3 = *(const float4*)&T[(size_t)i3 * 32 + sub * 8];
        float m0 = (p0 < s1) ? 1.f : 0.f;
        float m1 = (p1 < s1) ? 1.f : 0.f;
        float m2 = (p2 < s1) ? 1.f : 0.f;
        float m3 = (p3 < s1) ? 1.f : 0.f;
        ACC8(r0, m0);
        ACC8(r1, m1);
        ACC8(r2, m2);
        ACC8(r3, m3);
        for (int k = s0 + 32 + g; k < s1; k += 8) {  // rare (deg>32)
            int iv = csr[k];
            float4 rv = *(const float4*)&T[(size_t)iv * 32 + sub * 8];
            ACC8(rv, 1.f);
        }
    }

#pragma unroll
    for (int j = 0; j < 8; ++j) {
        acc[j] += __shfl_xor(acc[j], 4, 64);
        acc[j] += __shfl_xor(acc[j], 8, 64);
        acc[j] += __shfl_xor(acc[j], 16, 64);
    }

    if (g == 0 && valid) {
        int e0 = sub * 8;
        float4 sr = *(const float4*)&T[(size_t)nodec * 32 + e0];
        const __half2* sh = (const __half2*)&sr;
        float di = dinv[nodec];
        float2 f0 = __half22float2(sh[0]);
        float2 f1 = __half22float2(sh[1]);
        float2 f2 = __half22float2(sh[2]);
        float2 f3 = __half22float2(sh[3]);
        float4 outv;
        __half2* op = (__half2*)&outv;
        op[0] = __floats2half2_rn((acc[0] + f0.x) * di, (acc[1] + f0.y) * di);
        op[1] = __floats2half2_rn((acc[2] + f1.x) * di, (acc[3] + f1.y) * di);
        op[2] = __floats2half2_rn((acc[4] + f2.x) * di, (acc[5] + f2.y) * di);
        op[3] = __floats2half2_rn((acc[6] + f3.x) * di, (acc[7] + f3.y) * di);
        *(float4*)&gh2[(size_t)node * 64 + half * 32 + e0] = outv;
    }
}

// mu|sig GEMM (MFMA, f16 A direct from gh2) + bias + elu + pool stage-1
// (LDS column reduce with boundary-flush atomics into sums).
__global__ __launch_bounds__(256) void k_mm_pool(const __half* __restrict__ gh2,
                                                 const __half* __restrict__ Fmu,
                                                 const __half* __restrict__ Fsig,
                                                 const float* __restrict__ bmu,
                                                 const float* __restrict__ bsig,
                                                 const int* __restrict__ batch,
                                                 float* __restrict__ sums, int n) {
    __shared__ float wc[64 * 132];
    __shared__ int bs[64];
    const int tid = threadIdx.x;
    int l = tid & 63, wave = tid >> 6;
    int m0 = blockIdx.x * 64;
    int row_a = m0 + wave * 16 + (l & 15);
    if (row_a >= n) row_a = n - 1;
    int kg = l >> 4;

    f32x4 am[4], as[4];
#pragma unroll
    for (int ct = 0; ct < 4; ++ct) {
        am[ct] = (f32x4){0.f, 0.f, 0.f, 0.f};
        as[ct] = (f32x4){0.f, 0.f, 0.f, 0.f};
    }

    const __half* gr = gh2 + (size_t)row_a * 64 + kg * 8;
#pragma unroll
    for (int ks = 0; ks < 2; ++ks) {
        half8 a = *(const half8*)(gr + ks * 32);
        const __half* fm = Fmu + ((size_t)(ks * 4) * 64 + l) * 8;
        const __half* fs = Fsig + ((size_t)(ks * 4) * 64 + l) * 8;
#pragma unroll
        for (int ct = 0; ct < 4; ++ct) {
            half8 bm = *(const half8*)(fm + ct * 512);
            half8 bv = *(const half8*)(fs + ct * 512);
            am[ct] = __builtin_amdgcn_mfma_f32_16x16x32_f16(a, bm, am[ct], 0, 0, 0);
            as[ct] = __builtin_amdgcn_mfma_f32_16x16x32_f16(a, bv, as[ct], 0, 0, 0);
        }
    }

    if (tid < 64) bs[tid] = (m0 + tid < n) ? batch[m0 + tid] : -1;

    int col = l & 15;
#pragma unroll
    for (int ct = 0; ct < 4; ++ct) {
        float bM = bmu[ct * 16 + col];
        float bS = bsig[ct * 16 + col];
#pragma unroll
        for (int r = 0; r < 4; ++r) {
            int rr = wave * 16 + kg * 4 + r;  // C/D row mapping
            wc[rr * 132 + ct * 16 + col] = elu1(am[ct][r] + bM);
            wc[rr * 132 + 64 + ct * 16 + col] = elu1(as[ct][r] + bS);
        }
    }
    __syncthreads();

    // Pool: thread (d, seg) reduces column d over rows [seg*32, seg*32+32),
    // flushing at graph boundaries (batch sorted).
    int d = tid & 127, seg = tid >> 7;
    int base = (d < 64) ? d : (64 * 64 - 64 + d);  // mu: g*64+d, sig: 4096+g*64+(d-64)
    float acc = 0.f;
    int gcur = -1;
    int r0 = seg * 32;
    for (int r = r0; r < r0 + 32; ++r) {
        int gb = bs[r];
        if (gb < 0) break;
        float v = wc[r * 132 + d];
        if (gb != gcur) {
            if (gcur >= 0) atomicAdd(&sums[base + gcur * 64], acc);
            acc = 0.f;
            gcur = gb;
        }
        acc += v;
    }
    if (gcur >= 0) atomicAdd(&sums[base + gcur * 64], acc);
}

// Pool stage 2: one thread per output element; cnt via binary search.
__global__ void k_pool_final(const float* __restrict__ sums,
                             const int* __restrict__ batch,
                             float* __restrict__ out, int n) {
    int i = blockIdx.x * blockDim.x + threadIdx.x;
    if (i >= 2 * N_GRAPHS * ZDIM) return;
    int g = (i >> 6) & 63;
    int lo = 0, hi = n;
    while (lo < hi) { int m = (lo + hi) >> 1; if (batch[m] < g) lo = m + 1; else hi = m; }
    int s = lo;
    lo = s; hi = n;
    while (lo < hi) { int m = (lo + hi) >> 1; if (batch[m] < g + 1) lo = m + 1; else hi = m; }
    float c = fmaxf((float)(lo - s), 1.0f);
    out[i] = sums[i] / c;
}

extern "C" void kernel_launch(void* const* d_in, const int* in_sizes, int n_in,
                              void* d_out, int out_size, void* d_ws, size_t ws_size,
                              hipStream_t stream) {
    const float* x    = (const float*)d_in[0];
    const int*   ei   = (const int*)d_in[1];
    const int*   batch= (const int*)d_in[2];
    // d_in[3] = num_graphs (scalar, known 64)
    const float* W1   = (const float*)d_in[4];
    const float* b1   = (const float*)d_in[5];
    const float* Wmu  = (const float*)d_in[6];
    const float* bmu  = (const float*)d_in[7];
    const float* Wsig = (const float*)d_in[8];
    const float* bsig = (const float*)d_in[9];
    float* out = (float*)d_out;

    const int n = in_sizes[0] / IN_DIM;   // 50000
    const int E = in_sizes[1] / 2;        // 800000
    const int* src = ei;
    const int* dst = ei + E;
    const int NSB = (n + SCAN_B - 1) / SCAN_B;  // scan blocks (49)

    float* ws = (float*)d_ws;
    size_t off_w = 0;
    int*   kc   = (int*)(ws + off_w); off_w += 50048;
    float* sums = ws + off_w; off_w += 8192;   // contiguous with kc: one memset
    float* dinv = ws + off_w; off_w += 50048;
    int*   offs = (int*)(ws + off_w); off_w += 50056;
    int*   bsum = (int*)(ws + off_w); off_w += 64;
    int*   rank = (int*)(ws + off_w); off_w += 800000;
    int*   csr  = (int*)(ws + off_w); off_w += 800000;
    off_w = (off_w + 15) & ~(size_t)15;
    __half* F1   = (__half*)(ws + off_w); off_w += 4096;  // 8192 halfs
    __half* Fmu  = (__half*)(ws + off_w); off_w += 2048;  // 4096 halfs
    __half* Fsig = (__half*)(ws + off_w); off_w += 2048;  // 4096 halfs
    const size_t HALFF = (size_t)50048 * 16;  // n*32 halfs, in float units
    __half* tsA = (__half*)(ws + off_w); off_w += HALFF;  // dims 0..31
    __half* tsB = (__half*)(ws + off_w); off_w += HALFF;  // dims 32..63
    __half* hhA = (__half*)(ws + off_w); off_w += HALFF;
    __half* hhB = (__half*)(ws + off_w); off_w += HALFF;
    __half* gh2 = (__half*)(ws + off_w); off_w += (size_t)50048 * 32;  // n*64 halfs

    const int gE2 = (E + 511) / 512;  // 2-edges-per-thread blocks (1563)
    const int NB  = (n + 63) / 64;    // 64-node GEMM tiles
    const int bph = (n + 7) / 8;      // gather blocks per half (8 nodes/blk)
    const int bph4 = (bph + 3) & ~3;  // multiple of 4 -> grid multiple of 8
    const int gG = 2 * bph4;          // split-half gather grid

    // CSR build + normalization (kc+sums zeroed in ONE contiguous memset)
    hipMemsetAsync(kc, 0, (50048 + 8192) * sizeof(int), stream);
    k_count_wfrag<<<gE2 + 32, 256, 0, stream>>>(dst, kc, rank, E,
                                                W1, Wmu, Wsig, F1, Fmu, Fsig, gE2);
    k_scan1<<<NSB, SCAN_B, 0, stream>>>(kc, bsum, n);
    k_scan3<<<NSB, SCAN_B, 0, stream>>>(kc, bsum, offs, dinv, n, NSB);

    // CSR fill + layer-1 MFMA GEMM (split ts epilogue)
    k_fill_mm1<<<gE2 + NB, 256, 0, stream>>>(src, dst, rank, offs, csr, E,
                                             x, F1, dinv, tsA, tsB, n, gE2);

    // layer 1 gather: hhA|hhB = fp16(dinv*elu(S(xW1)+b1)), XCD-affine halves
    k_gather_hh<<<gG, 256, 0, stream>>>(offs, csr, dinv, tsA, tsB, b1, hhA, hhB, n);

    // layers 2/3 shared gather: gh2 = f16(S*h), XCD-affine halves
    k_gather_g<<<gG, 256, 0, stream>>>(offs, csr, dinv, hhA, hhB, gh2, n);

    // mu|sig MFMA GEMM + bias + elu + fused pool stage-1
    k_mm_pool<<<NB, 256, 0, stream>>>(gh2, Fmu, Fsig, bmu, bsig, batch, sums, n);
    k_pool_final<<<(2 * N_GRAPHS * ZDIM + 255) / 256, 256, 0, stream>>>(sums, batch, out, n);
}